// Round 1
// baseline (245.078 us; speedup 1.0000x reference)
//
#include <hip/hip_runtime.h>

// EM_fusion: softmax over two identical logits == exactly 0.5, so
// fused = 0.5*(feature_1 + feature_2). Pure memory-bound elementwise op.
// B*D = 131072*768 = 100,663,296 fp32 elements, divisible by 4.

__global__ __launch_bounds__(256) void EM_fusion_avg_kernel(
    const float4* __restrict__ f1,
    const float4* __restrict__ f2,
    float4* __restrict__ out,
    long n4)
{
    long i = (long)blockIdx.x * blockDim.x + threadIdx.x;
    const long stride = (long)gridDim.x * blockDim.x;
    for (; i < n4; i += stride) {
        float4 a = f1[i];
        float4 b = f2[i];
        float4 r;
        r.x = 0.5f * (a.x + b.x);
        r.y = 0.5f * (a.y + b.y);
        r.z = 0.5f * (a.z + b.z);
        r.w = 0.5f * (a.w + b.w);
        out[i] = r;
    }
}

extern "C" void kernel_launch(void* const* d_in, const int* in_sizes, int n_in,
                              void* d_out, int out_size, void* d_ws, size_t ws_size,
                              hipStream_t stream)
{
    const float* f1 = (const float*)d_in[0];
    const float* f2 = (const float*)d_in[1];
    float* out = (float*)d_out;

    const long n = (long)in_sizes[0];   // 100,663,296
    const long n4 = n / 4;              // 25,165,824 (exact)

    const int block = 256;
    const int grid = 2048;              // 256 CU x 8 blocks, grid-stride covers the rest

    EM_fusion_avg_kernel<<<grid, block, 0, stream>>>(
        (const float4*)f1, (const float4*)f2, (float4*)out, n4);
}